// Round 1
// baseline (636.075 us; speedup 1.0000x reference)
//
#include <hip/hip_runtime.h>
#include <hip/hip_bf16.h>
#include <cstdint>
#include <cstddef>

typedef __bf16 bf16_t;
typedef __attribute__((ext_vector_type(8))) __bf16 bf16x8;
typedef __attribute__((ext_vector_type(4))) float f32x4;

#define S_ 2048
#define H_ 16
#define NTOK 4096

__device__ __forceinline__ f32x4 mfma16x16(bf16x8 a, bf16x8 b, f32x4 c) {
  return __builtin_amdgcn_mfma_f32_16x16x32_bf16(a, b, c, 0, 0, 0);
}
__device__ __forceinline__ bf16x8 load8(const bf16_t* p) {
  return *reinterpret_cast<const bf16x8*>(p);
}
__device__ __forceinline__ void load_lds16(const void* g, void* l) {
  __builtin_amdgcn_global_load_lds(
      (const __attribute__((address_space(1))) uint32_t*)g,
      (__attribute__((address_space(3))) uint32_t*)l, 16, 0, 0);
}

// ---------------- prep kernels ----------------

__global__ void cast_bf16_k(const float* __restrict__ in, bf16_t* __restrict__ out, int n) {
  int idx = blockIdx.x * 256 + threadIdx.x;
  int i4 = idx * 4;
  if (i4 >= n) return;
  float4 v = *reinterpret_cast<const float4*>(in + i4);
  out[i4 + 0] = (bf16_t)v.x;
  out[i4 + 1] = (bf16_t)v.y;
  out[i4 + 2] = (bf16_t)v.z;
  out[i4 + 3] = (bf16_t)v.w;
}

// in: K x Nsrc (f32 row-major), out: Nout x K (bf16 row-major), cols >= Nsrc zero-padded
__global__ void transpose_cast_k(const float* __restrict__ in, bf16_t* __restrict__ out,
                                 int K, int Nsrc, int Nout) {
  __shared__ float tile[32][33];
  int k0 = blockIdx.y * 32, n0 = blockIdx.x * 32;
  int tx = threadIdx.x & 31, ty = threadIdx.x >> 5;  // 256 threads: ty 0..7
#pragma unroll
  for (int i = 0; i < 4; ++i) {
    int k = k0 + ty + i * 8, n = n0 + tx;
    tile[ty + i * 8][tx] = (n < Nsrc) ? in[(size_t)k * Nsrc + n] : 0.0f;
  }
  __syncthreads();
#pragma unroll
  for (int i = 0; i < 4; ++i) {
    int n = n0 + ty + i * 8, k = k0 + tx;
    out[(size_t)n * K + k] = (bf16_t)tile[tx][ty + i * 8];
  }
}

__global__ void rope_tables_k(float* __restrict__ cosT, float* __restrict__ sinT) {
  int idx = blockIdx.x * 256 + threadIdx.x;
  if (idx >= S_ * 32) return;
  int s = idx >> 5, i = idx & 31;
  float inv = powf(10000.0f, -(2.0f * (float)i) / 64.0f);
  float fr = (float)s * inv;
  cosT[idx] = cosf(fr);
  sinT[idx] = sinf(fr);
}

// rotate pairs (2i, 2i+1) within [off + h*hstride .. +64) of each token row
__global__ void rope_apply_k(bf16_t* __restrict__ buf, const float* __restrict__ cosT,
                             const float* __restrict__ sinT, int ld, int nh, int hstride, int off) {
  int idx = blockIdx.x * 256 + threadIdx.x;
  int total = NTOK * nh * 32;
  if (idx >= total) return;
  int i = idx & 31;
  int h = (idx >> 5) % nh;
  int t = idx / (32 * nh);
  int s = t & (S_ - 1);
  float c = cosT[s * 32 + i], sn = sinT[s * 32 + i];
  bf16_t* p = buf + (size_t)t * ld + off + h * hstride + 2 * i;
  float xe = (float)p[0], xo = (float)p[1];
  p[0] = (bf16_t)(xe * c - xo * sn);
  p[1] = (bf16_t)(xo * c + xe * sn);
}

// ---------------- GEMM: C(MxN) = A(MxK, lda) @ Bt(NxK)^T, 128x128 tile ----------------

template <int OUT_F32>
__global__ __launch_bounds__(256) void gemm_bf16(const bf16_t* __restrict__ A, int lda,
                                                 const bf16_t* __restrict__ Bt,
                                                 void* __restrict__ Cv, int M, int N, int K,
                                                 float scale) {
  __shared__ alignas(16) bf16_t Al[128 * 32];
  __shared__ alignas(16) bf16_t Bl[128 * 32];
  const int tid = threadIdx.x;
  const int wid = tid >> 6, lane = tid & 63;
  const int m0 = blockIdx.y * 128, n0 = blockIdx.x * 128;
  const int wm = (wid >> 1) * 64, wn = (wid & 1) * 64;

  f32x4 acc[4][4] = {};

  const int srow = wid * 32 + (lane >> 2);
  const int scol = (lane & 3) * 8;
  const bf16_t* ag0 = A + (size_t)(m0 + srow) * lda + scol;
  const bf16_t* ag1 = A + (size_t)(m0 + srow + 16) * lda + scol;
  const bf16_t* bg0 = Bt + (size_t)(n0 + srow) * K + scol;
  const bf16_t* bg1 = Bt + (size_t)(n0 + srow + 16) * K + scol;
  bf16_t* al0 = &Al[wid * 1024];
  bf16_t* al1 = &Al[wid * 1024 + 512];
  bf16_t* bl0 = &Bl[wid * 1024];
  bf16_t* bl1 = &Bl[wid * 1024 + 512];

  const int lr = lane & 15, lk = (lane >> 4) * 8;

  for (int k0 = 0; k0 < K; k0 += 32) {
    load_lds16(ag0 + k0, al0);
    load_lds16(ag1 + k0, al1);
    load_lds16(bg0 + k0, bl0);
    load_lds16(bg1 + k0, bl1);
    __syncthreads();
    bf16x8 af[4], bfr[4];
#pragma unroll
    for (int i = 0; i < 4; ++i) {
      af[i] = load8(&Al[(wm + i * 16 + lr) * 32 + lk]);
      bfr[i] = load8(&Bl[(wn + i * 16 + lr) * 32 + lk]);
    }
#pragma unroll
    for (int i = 0; i < 4; ++i)
#pragma unroll
      for (int j = 0; j < 4; ++j) acc[i][j] = mfma16x16(af[i], bfr[j], acc[i][j]);
    __syncthreads();
  }

  const int lg = lane >> 4;
  if (OUT_F32) {
    float* C = (float*)Cv;
#pragma unroll
    for (int i = 0; i < 4; ++i)
#pragma unroll
      for (int j = 0; j < 4; ++j)
#pragma unroll
        for (int r = 0; r < 4; ++r) {
          int row = m0 + wm + i * 16 + lg * 4 + r;
          int col = n0 + wn + j * 16 + lr;
          C[(size_t)row * N + col] = acc[i][j][r] * scale;
        }
  } else {
    bf16_t* C = (bf16_t*)Cv;
#pragma unroll
    for (int i = 0; i < 4; ++i)
#pragma unroll
      for (int j = 0; j < 4; ++j)
#pragma unroll
        for (int r = 0; r < 4; ++r) {
          int row = m0 + wm + i * 16 + lg * 4 + r;
          int col = n0 + wn + j * 16 + lr;
          C[(size_t)row * N + col] = (bf16_t)(acc[i][j][r] * scale);
        }
  }
}

// ---------------- fused causal flash attention ----------------
// q:   [4096][2048] bf16 (pre-scaled by 1/sqrt(128), q_pe roped)  col = h*128 + d
// kv:  [4096][3072] bf16  col = h*192 + {k_nope(64) | v(128)}
// lat: [4096][2176] bf16  cols 2048..2111 = roped k_pe (shared across heads)
// out: [4096][2048] bf16  col = h*128 + d
__global__ __launch_bounds__(256) void attn_fused(const bf16_t* __restrict__ q,
                                                  const bf16_t* __restrict__ kv,
                                                  const bf16_t* __restrict__ lat,
                                                  bf16_t* __restrict__ out) {
  __shared__ alignas(16) bf16_t Vt[128][72];
  __shared__ alignas(16) bf16_t Pl[4][16][72];
  const int tid = threadIdx.x, wid = tid >> 6, lane = tid & 63;
  const int qt = blockIdx.x;  // 0..31
  const int bh = blockIdx.y;  // 0..31
  const int b = bh >> 4, h = bh & 15;
  const int tokb = b * S_;
  const int lr = lane & 15, lg = lane >> 4;

  // Q fragments (held in registers for the whole block)
  bf16x8 qf[4];
  {
    const int qrow = qt * 64 + wid * 16 + lr;
    const bf16_t* qp = q + (size_t)(tokb + qrow) * 2048 + h * 128 + lg * 8;
#pragma unroll
    for (int ds = 0; ds < 4; ++ds) qf[ds] = load8(qp + ds * 32);
  }

  f32x4 o[8] = {};
  float mrow[4] = {-1e30f, -1e30f, -1e30f, -1e30f};
  float lrow[4] = {0.f, 0.f, 0.f, 0.f};

  for (int t = 0; t <= qt; ++t) {
    const int kb = t * 64;
    // stage V^T into LDS
    {
      const int key = tid >> 4;
      const int d0 = (tid & 15) * 8;
#pragma unroll
      for (int rep = 0; rep < 4; ++rep) {
        const bf16_t* vp = kv + (size_t)(tokb + kb + key + rep * 16) * 3072 + h * 192 + 64 + d0;
        bf16x8 v = load8(vp);
#pragma unroll
        for (int j = 0; j < 8; ++j) Vt[d0 + j][key + rep * 16] = v[j];
      }
    }
    __syncthreads();

    // S = Q K^T  (16 q-rows x 64 keys per wave)
    f32x4 s[4];
#pragma unroll
    for (int kt = 0; kt < 4; ++kt) {
      s[kt] = f32x4{0.f, 0.f, 0.f, 0.f};
      const size_t tk = (size_t)(tokb + kb + kt * 16 + lr);
      const bf16_t* kp0 = kv + tk * 3072 + h * 192 + lg * 8;
      const bf16_t* kp1 = lat + tk * 2176 + 2048 + lg * 8;
      bf16x8 kf0 = load8(kp0);
      bf16x8 kf1 = load8(kp0 + 32);
      bf16x8 kf2 = load8(kp1);
      bf16x8 kf3 = load8(kp1 + 32);
      s[kt] = mfma16x16(qf[0], kf0, s[kt]);
      s[kt] = mfma16x16(qf[1], kf1, s[kt]);
      s[kt] = mfma16x16(qf[2], kf2, s[kt]);
      s[kt] = mfma16x16(qf[3], kf3, s[kt]);
    }

    if (t == qt) {  // causal mask on diagonal tile
#pragma unroll
      for (int kt = 0; kt < 4; ++kt) {
        const int key = kb + kt * 16 + lr;
#pragma unroll
        for (int r = 0; r < 4; ++r) {
          const int qr = qt * 64 + wid * 16 + lg * 4 + r;
          if (key > qr) s[kt][r] = -1e30f;
        }
      }
    }

    // online softmax over the 64-key tile
    float corr[4];
#pragma unroll
    for (int r = 0; r < 4; ++r) {
      float mx = fmaxf(fmaxf(s[0][r], s[1][r]), fmaxf(s[2][r], s[3][r]));
      mx = fmaxf(mx, __shfl_xor(mx, 1));
      mx = fmaxf(mx, __shfl_xor(mx, 2));
      mx = fmaxf(mx, __shfl_xor(mx, 4));
      mx = fmaxf(mx, __shfl_xor(mx, 8));
      float mn = fmaxf(mrow[r], mx);
      corr[r] = __expf(mrow[r] - mn);
      mrow[r] = mn;
    }
    float psum[4] = {0.f, 0.f, 0.f, 0.f};
#pragma unroll
    for (int kt = 0; kt < 4; ++kt)
#pragma unroll
      for (int r = 0; r < 4; ++r) {
        float p = __expf(s[kt][r] - mrow[r]);
        s[kt][r] = p;
        psum[r] += p;
      }
#pragma unroll
    for (int r = 0; r < 4; ++r) {
      float ps = psum[r];
      ps += __shfl_xor(ps, 1);
      ps += __shfl_xor(ps, 2);
      ps += __shfl_xor(ps, 4);
      ps += __shfl_xor(ps, 8);
      lrow[r] = lrow[r] * corr[r] + ps;
    }
#pragma unroll
    for (int n = 0; n < 8; ++n)
#pragma unroll
      for (int r = 0; r < 4; ++r) o[n][r] *= corr[r];

    // stage P (bf16) to per-wave LDS
#pragma unroll
    for (int kt = 0; kt < 4; ++kt)
#pragma unroll
      for (int r = 0; r < 4; ++r) Pl[wid][lg * 4 + r][kt * 16 + lr] = (bf16_t)s[kt][r];
    __syncthreads();

    // O += P @ V
#pragma unroll
    for (int ks = 0; ks < 2; ++ks) {
      bf16x8 pa = load8(&Pl[wid][lr][ks * 32 + lg * 8]);
#pragma unroll
      for (int n = 0; n < 8; ++n) {
        bf16x8 vb = load8(&Vt[n * 16 + lr][ks * 32 + lg * 8]);
        o[n] = mfma16x16(pa, vb, o[n]);
      }
    }
    __syncthreads();
  }

  // epilogue: divide by l, store
#pragma unroll
  for (int n = 0; n < 8; ++n)
#pragma unroll
    for (int r = 0; r < 4; ++r) {
      const int qr = qt * 64 + wid * 16 + lg * 4 + r;
      float val = o[n][r] / lrow[r];
      out[(size_t)(tokb + qr) * 2048 + h * 128 + n * 16 + lr] = (bf16_t)val;
    }
}

// ---------------- launch ----------------

extern "C" void kernel_launch(void* const* d_in, const int* in_sizes, int n_in, void* d_out,
                              int out_size, void* d_ws, size_t ws_size, hipStream_t stream) {
  const float* hs = (const float*)d_in[0];
  const float* Wqa = (const float*)d_in[1];
  const float* Wqb = (const float*)d_in[2];
  const float* Wkva = (const float*)d_in[3];
  const float* Wkvb = (const float*)d_in[4];
  const float* Wo = (const float*)d_in[5];
  float* out = (float*)d_out;

  char* ws = (char*)d_ws;
  size_t off = 0;
  auto alloc = [&](size_t bytes) {
    void* p = ws + off;
    off += (bytes + 255) & ~(size_t)255;
    return p;
  };
  bf16_t* hsb = (bf16_t*)alloc((size_t)NTOK * 2048 * 2);
  bf16_t* W1t = (bf16_t*)alloc((size_t)2176 * 2048 * 2);
  bf16_t* Wqbt = (bf16_t*)alloc((size_t)2048 * 1536 * 2);
  bf16_t* Wkvbt = (bf16_t*)alloc((size_t)3072 * 512 * 2);
  bf16_t* Wot = (bf16_t*)alloc((size_t)2048 * 2048 * 2);
  bf16_t* lat = (bf16_t*)alloc((size_t)NTOK * 2176 * 2);
  bf16_t* qb = (bf16_t*)alloc((size_t)NTOK * 2048 * 2);
  bf16_t* kvb = (bf16_t*)alloc((size_t)NTOK * 3072 * 2);
  bf16_t* attn = (bf16_t*)alloc((size_t)NTOK * 2048 * 2);
  float* cosT = (float*)alloc((size_t)S_ * 32 * 4);
  float* sinT = (float*)alloc((size_t)S_ * 32 * 4);

  // prep
  cast_bf16_k<<<(NTOK * 2048 / 4 + 255) / 256, 256, 0, stream>>>(hs, hsb, NTOK * 2048);
  transpose_cast_k<<<dim3(1536 / 32, 2048 / 32), 256, 0, stream>>>(Wqa, W1t, 2048, 1536, 1536);
  transpose_cast_k<<<dim3(640 / 32, 2048 / 32), 256, 0, stream>>>(Wkva, W1t + (size_t)1536 * 2048,
                                                                  2048, 576, 640);
  transpose_cast_k<<<dim3(2048 / 32, 1536 / 32), 256, 0, stream>>>(Wqb, Wqbt, 1536, 2048, 2048);
  transpose_cast_k<<<dim3(3072 / 32, 512 / 32), 256, 0, stream>>>(Wkvb, Wkvbt, 512, 3072, 3072);
  transpose_cast_k<<<dim3(2048 / 32, 2048 / 32), 256, 0, stream>>>(Wo, Wot, 2048, 2048, 2048);
  rope_tables_k<<<(S_ * 32 + 255) / 256, 256, 0, stream>>>(cosT, sinT);

  // lat = hsb @ [Wqa | Wkva(pad to 640)]   (4096 x 2176, K=2048)
  gemm_bf16<0><<<dim3(2176 / 128, NTOK / 128), 256, 0, stream>>>(hsb, 2048, W1t, lat, NTOK, 2176,
                                                                 2048, 1.0f);
  // rope k_pe (lat cols 2048..2111)
  rope_apply_k<<<(NTOK * 32 + 255) / 256, 256, 0, stream>>>(lat, cosT, sinT, 2176, 1, 0, 2048);
  // q = q_latent @ Wqb, scaled by 1/sqrt(128)
  const float scale = 0.08838834764831845f;
  gemm_bf16<0><<<dim3(2048 / 128, NTOK / 128), 256, 0, stream>>>(lat, 2176, Wqbt, qb, NTOK, 2048,
                                                                 1536, scale);
  rope_apply_k<<<(NTOK * 16 * 32 + 255) / 256, 256, 0, stream>>>(qb, cosT, sinT, 2048, 16, 128, 64);
  // kv = c_kv @ Wkvb
  gemm_bf16<0><<<dim3(3072 / 128, NTOK / 128), 256, 0, stream>>>(lat + 1536, 2176, Wkvbt, kvb, NTOK,
                                                                 3072, 512, 1.0f);
  // attention
  attn_fused<<<dim3(32, 32), 256, 0, stream>>>(qb, kvb, lat, attn);
  // out = attn @ Wo (f32 output)
  gemm_bf16<1><<<dim3(2048 / 128, NTOK / 128), 256, 0, stream>>>(attn, 2048, Wot, out, NTOK, 2048,
                                                                 2048, 1.0f);
}

// Round 2
// 328.494 us; speedup vs baseline: 1.9363x; 1.9363x over previous
//
#include <hip/hip_runtime.h>
#include <hip/hip_bf16.h>
#include <cstdint>
#include <cstddef>

typedef __bf16 bf16_t;
typedef __attribute__((ext_vector_type(8))) __bf16 bf16x8;
typedef __attribute__((ext_vector_type(4))) float f32x4;

#define S_ 2048
#define H_ 16
#define NTOK 4096

__device__ __forceinline__ f32x4 mfma16x16(bf16x8 a, bf16x8 b, f32x4 c) {
  return __builtin_amdgcn_mfma_f32_16x16x32_bf16(a, b, c, 0, 0, 0);
}
__device__ __forceinline__ bf16x8 load8(const bf16_t* p) {
  return *reinterpret_cast<const bf16x8*>(p);
}
__device__ __forceinline__ void load_lds16(const void* g, void* l) {
  __builtin_amdgcn_global_load_lds(
      (const __attribute__((address_space(1))) uint32_t*)g,
      (__attribute__((address_space(3))) uint32_t*)l, 16, 0, 0);
}

// ---------------- prep kernels ----------------

__global__ void cast_bf16_k(const float* __restrict__ in, bf16_t* __restrict__ out, int n) {
  int idx = blockIdx.x * 256 + threadIdx.x;
  int i4 = idx * 4;
  if (i4 >= n) return;
  float4 v = *reinterpret_cast<const float4*>(in + i4);
  out[i4 + 0] = (bf16_t)v.x;
  out[i4 + 1] = (bf16_t)v.y;
  out[i4 + 2] = (bf16_t)v.z;
  out[i4 + 3] = (bf16_t)v.w;
}

// in: K x Nsrc (f32 row-major), out: Nout x K (bf16 row-major), cols >= Nsrc zero-padded
__global__ void transpose_cast_k(const float* __restrict__ in, bf16_t* __restrict__ out,
                                 int K, int Nsrc, int Nout) {
  __shared__ float tile[32][33];
  int k0 = blockIdx.y * 32, n0 = blockIdx.x * 32;
  int tx = threadIdx.x & 31, ty = threadIdx.x >> 5;  // 256 threads: ty 0..7
#pragma unroll
  for (int i = 0; i < 4; ++i) {
    int k = k0 + ty + i * 8, n = n0 + tx;
    tile[ty + i * 8][tx] = (n < Nsrc) ? in[(size_t)k * Nsrc + n] : 0.0f;
  }
  __syncthreads();
#pragma unroll
  for (int i = 0; i < 4; ++i) {
    int n = n0 + ty + i * 8, k = k0 + tx;
    out[(size_t)n * K + k] = (bf16_t)tile[tx][ty + i * 8];
  }
}

// V^T: vT[(bh*128 + d)*2048 + s] = kv[(b*2048+s)*3072 + h*192 + 64 + d]
__global__ void transpose_v_k(const bf16_t* __restrict__ kv, bf16_t* __restrict__ vT) {
  __shared__ bf16_t tile[32][33];
  int bh = blockIdx.z;
  int b = bh >> 4, h = bh & 15;
  int s0 = blockIdx.x * 32, d0 = blockIdx.y * 32;
  int tx = threadIdx.x & 31, ty = threadIdx.x >> 5;
#pragma unroll
  for (int i = 0; i < 4; ++i) {
    int s = s0 + ty + i * 8;
    tile[ty + i * 8][tx] = kv[(size_t)(b * S_ + s) * 3072 + h * 192 + 64 + d0 + tx];
  }
  __syncthreads();
#pragma unroll
  for (int i = 0; i < 4; ++i) {
    int d = d0 + ty + i * 8;
    vT[((size_t)bh * 128 + d) * 2048 + s0 + tx] = tile[tx][ty + i * 8];
  }
}

__global__ void rope_tables_k(float* __restrict__ cosT, float* __restrict__ sinT) {
  int idx = blockIdx.x * 256 + threadIdx.x;
  if (idx >= S_ * 32) return;
  int s = idx >> 5, i = idx & 31;
  float inv = powf(10000.0f, -(2.0f * (float)i) / 64.0f);
  float fr = (float)s * inv;
  cosT[idx] = cosf(fr);
  sinT[idx] = sinf(fr);
}

// rotate pairs (2i, 2i+1) within [off + h*hstride .. +64) of each token row
__global__ void rope_apply_k(bf16_t* __restrict__ buf, const float* __restrict__ cosT,
                             const float* __restrict__ sinT, int ld, int nh, int hstride, int off) {
  int idx = blockIdx.x * 256 + threadIdx.x;
  int total = NTOK * nh * 32;
  if (idx >= total) return;
  int i = idx & 31;
  int h = (idx >> 5) % nh;
  int t = idx / (32 * nh);
  int s = t & (S_ - 1);
  float c = cosT[s * 32 + i], sn = sinT[s * 32 + i];
  bf16_t* p = buf + (size_t)t * ld + off + h * hstride + 2 * i;
  float xe = (float)p[0], xo = (float)p[1];
  p[0] = (bf16_t)(xe * c - xo * sn);
  p[1] = (bf16_t)(xo * c + xe * sn);
}

// ---------------- GEMM: C(MxN) = A(MxK, lda) @ Bt(NxK)^T, 128x128 tile ----------------

template <int OUT_F32>
__global__ __launch_bounds__(256) void gemm_bf16(const bf16_t* __restrict__ A, int lda,
                                                 const bf16_t* __restrict__ Bt,
                                                 void* __restrict__ Cv, int M, int N, int K,
                                                 float scale) {
  __shared__ alignas(16) bf16_t Al[128 * 32];
  __shared__ alignas(16) bf16_t Bl[128 * 32];
  const int tid = threadIdx.x;
  const int wid = tid >> 6, lane = tid & 63;
  const int m0 = blockIdx.y * 128, n0 = blockIdx.x * 128;
  const int wm = (wid >> 1) * 64, wn = (wid & 1) * 64;

  f32x4 acc[4][4] = {};

  const int srow = wid * 32 + (lane >> 2);
  const int scol = (lane & 3) * 8;
  const bf16_t* ag0 = A + (size_t)(m0 + srow) * lda + scol;
  const bf16_t* ag1 = A + (size_t)(m0 + srow + 16) * lda + scol;
  const bf16_t* bg0 = Bt + (size_t)(n0 + srow) * K + scol;
  const bf16_t* bg1 = Bt + (size_t)(n0 + srow + 16) * K + scol;
  bf16_t* al0 = &Al[wid * 1024];
  bf16_t* al1 = &Al[wid * 1024 + 512];
  bf16_t* bl0 = &Bl[wid * 1024];
  bf16_t* bl1 = &Bl[wid * 1024 + 512];

  const int lr = lane & 15, lk = (lane >> 4) * 8;

  for (int k0 = 0; k0 < K; k0 += 32) {
    load_lds16(ag0 + k0, al0);
    load_lds16(ag1 + k0, al1);
    load_lds16(bg0 + k0, bl0);
    load_lds16(bg1 + k0, bl1);
    __syncthreads();
    bf16x8 af[4], bfr[4];
#pragma unroll
    for (int i = 0; i < 4; ++i) {
      af[i] = load8(&Al[(wm + i * 16 + lr) * 32 + lk]);
      bfr[i] = load8(&Bl[(wn + i * 16 + lr) * 32 + lk]);
    }
#pragma unroll
    for (int i = 0; i < 4; ++i)
#pragma unroll
      for (int j = 0; j < 4; ++j) acc[i][j] = mfma16x16(af[i], bfr[j], acc[i][j]);
    __syncthreads();
  }

  const int lg = lane >> 4;
  if (OUT_F32) {
    float* C = (float*)Cv;
#pragma unroll
    for (int i = 0; i < 4; ++i)
#pragma unroll
      for (int j = 0; j < 4; ++j)
#pragma unroll
        for (int r = 0; r < 4; ++r) {
          int row = m0 + wm + i * 16 + lg * 4 + r;
          int col = n0 + wn + j * 16 + lr;
          C[(size_t)row * N + col] = acc[i][j][r] * scale;
        }
  } else {
    bf16_t* C = (bf16_t*)Cv;
#pragma unroll
    for (int i = 0; i < 4; ++i)
#pragma unroll
      for (int j = 0; j < 4; ++j)
#pragma unroll
        for (int r = 0; r < 4; ++r) {
          int row = m0 + wm + i * 16 + lg * 4 + r;
          int col = n0 + wn + j * 16 + lr;
          C[(size_t)row * N + col] = (bf16_t)(acc[i][j][r] * scale);
        }
  }
}

// ---------------- fused causal flash attention ----------------
// q:   [4096][2048] bf16 (pre-scaled, q_pe roped)  col = h*128 + d
// kv:  [4096][3072] bf16  col = h*192 + {k_nope(64) | v(128)}
// lat: [4096][2176] bf16  cols 2048..2111 = roped k_pe (shared across heads)
// vT:  [32][128][2048] bf16  (V transposed per (b,h))
// out: [4096][2048] bf16  col = h*128 + d
//
// 512 blocks; block bid handles q-tiles {pairi, 31-pairi} (33 key-tiles total:
// perfectly balanced triangle pairing). 4 waves x 16 q-rows. K/V staged via
// global_load_lds with both-sides XOR chunk swizzle (chunk ^= row&7).
__global__ __launch_bounds__(256) void attn_fused(const bf16_t* __restrict__ q,
                                                  const bf16_t* __restrict__ kv,
                                                  const bf16_t* __restrict__ lat,
                                                  const bf16_t* __restrict__ vT,
                                                  bf16_t* __restrict__ out) {
  __shared__ alignas(16) bf16_t Kn[64 * 64];
  __shared__ alignas(16) bf16_t Kp[64 * 64];
  __shared__ alignas(16) bf16_t Vt[128 * 64];
  __shared__ alignas(16) bf16_t Pl[4 * 16 * 64];
  const int tid = threadIdx.x, wid = tid >> 6, lane = tid & 63;
  const int bid = blockIdx.x;
  const int pairi = bid >> 5;  // 0..15
  const int bh = bid & 31;
  const int b = bh >> 4, h = bh & 15;
  const int tokb = b * S_;
  const int lr = lane & 15, lg = lane >> 4;
  const int srow8 = lane >> 3, c8 = lane & 7;
  const int swz8 = c8 ^ srow8;  // swizzled chunk for staging source
  bf16_t* Pw = &Pl[wid * 1024];

  for (int phase = 0; phase < 2; ++phase) {
    const int qt = phase ? (31 - pairi) : pairi;

    // Q fragments for this phase
    bf16x8 qf[4];
    {
      const int qrow = qt * 64 + wid * 16 + lr;
      const bf16_t* qp = q + (size_t)(tokb + qrow) * 2048 + h * 128 + lg * 8;
#pragma unroll
      for (int ds = 0; ds < 4; ++ds) qf[ds] = load8(qp + ds * 32);
    }

    f32x4 o[8] = {};
    float mrow[4] = {-1e30f, -1e30f, -1e30f, -1e30f};
    float lrow[4] = {0.f, 0.f, 0.f, 0.f};

    for (int t = 0; t <= qt; ++t) {
      const int kb = t * 64;
      // ---- stage Kn, Kp (64x64 each) and Vt (128x64) with source pre-swizzle ----
#pragma unroll
      for (int rr = 0; rr < 2; ++rr) {
        const int r0 = wid * 16 + rr * 8;
        const int row = r0 + srow8;
        const size_t tk = (size_t)(tokb + kb + row);
        load_lds16(kv + tk * 3072 + h * 192 + (swz8 << 3), &Kn[r0 * 64]);
        load_lds16(lat + tk * 2176 + 2048 + (swz8 << 3), &Kp[r0 * 64]);
      }
#pragma unroll
      for (int rr = 0; rr < 4; ++rr) {
        const int r0 = wid * 32 + rr * 8;
        const int row = r0 + srow8;
        load_lds16(vT + ((size_t)bh * 128 + row) * 2048 + kb + (swz8 << 3), &Vt[r0 * 64]);
      }
      __syncthreads();

      // ---- S = Q K^T  (16 q-rows x 64 keys per wave) ----
      f32x4 s[4];
#pragma unroll
      for (int kt = 0; kt < 4; ++kt) {
        const int row = kt * 16 + lr;
        const int e = lr & 7;
        bf16x8 kf0 = load8(&Kn[row * 64 + ((lg ^ e) << 3)]);
        bf16x8 kf1 = load8(&Kn[row * 64 + (((lg + 4) ^ e) << 3)]);
        bf16x8 kf2 = load8(&Kp[row * 64 + ((lg ^ e) << 3)]);
        bf16x8 kf3 = load8(&Kp[row * 64 + (((lg + 4) ^ e) << 3)]);
        f32x4 acc = {0.f, 0.f, 0.f, 0.f};
        acc = mfma16x16(qf[0], kf0, acc);
        acc = mfma16x16(qf[1], kf1, acc);
        acc = mfma16x16(qf[2], kf2, acc);
        acc = mfma16x16(qf[3], kf3, acc);
        s[kt] = acc;
      }

      if (t == qt) {  // causal mask on diagonal tile
#pragma unroll
        for (int kt = 0; kt < 4; ++kt) {
          const int key = kb + kt * 16 + lr;
#pragma unroll
          for (int r = 0; r < 4; ++r) {
            const int qr = qt * 64 + wid * 16 + lg * 4 + r;
            if (key > qr) s[kt][r] = -1e30f;
          }
        }
      }

      // ---- online softmax over the 64-key tile ----
      float corr[4];
#pragma unroll
      for (int r = 0; r < 4; ++r) {
        float mx = fmaxf(fmaxf(s[0][r], s[1][r]), fmaxf(s[2][r], s[3][r]));
        mx = fmaxf(mx, __shfl_xor(mx, 1));
        mx = fmaxf(mx, __shfl_xor(mx, 2));
        mx = fmaxf(mx, __shfl_xor(mx, 4));
        mx = fmaxf(mx, __shfl_xor(mx, 8));
        float mn = fmaxf(mrow[r], mx);
        corr[r] = __expf(mrow[r] - mn);
        mrow[r] = mn;
      }
      float psum[4] = {0.f, 0.f, 0.f, 0.f};
#pragma unroll
      for (int kt = 0; kt < 4; ++kt)
#pragma unroll
        for (int r = 0; r < 4; ++r) {
          float p = __expf(s[kt][r] - mrow[r]);
          s[kt][r] = p;
          psum[r] += p;
        }
#pragma unroll
      for (int r = 0; r < 4; ++r) {
        float ps = psum[r];
        ps += __shfl_xor(ps, 1);
        ps += __shfl_xor(ps, 2);
        ps += __shfl_xor(ps, 4);
        ps += __shfl_xor(ps, 8);
        lrow[r] = lrow[r] * corr[r] + ps;
      }
#pragma unroll
      for (int n = 0; n < 8; ++n)
#pragma unroll
        for (int r = 0; r < 4; ++r) o[n][r] *= corr[r];

      // ---- stage P (bf16) to per-wave LDS (chunk-swizzled; same-wave dep only) ----
#pragma unroll
      for (int kt = 0; kt < 4; ++kt)
#pragma unroll
        for (int r = 0; r < 4; ++r) {
          const int qrow = lg * 4 + r;
          const int key = kt * 16 + lr;
          Pw[qrow * 64 + ((((key >> 3) ^ (qrow & 7)) << 3) | (key & 7))] = (bf16_t)s[kt][r];
        }

      // ---- O += P @ V ----
#pragma unroll
      for (int ks = 0; ks < 2; ++ks) {
        const int e = lr & 7;
        bf16x8 pa = load8(&Pw[lr * 64 + (((ks * 4 + lg) ^ e) << 3)]);
#pragma unroll
        for (int n = 0; n < 8; ++n) {
          bf16x8 vb = load8(&Vt[(n * 16 + lr) * 64 + (((ks * 4 + lg) ^ e) << 3)]);
          o[n] = mfma16x16(pa, vb, o[n]);
        }
      }
      __syncthreads();
    }

    // ---- epilogue: divide by l, store ----
#pragma unroll
    for (int n = 0; n < 8; ++n)
#pragma unroll
      for (int r = 0; r < 4; ++r) {
        const int qr = qt * 64 + wid * 16 + lg * 4 + r;
        float val = o[n][r] / lrow[r];
        out[(size_t)(tokb + qr) * 2048 + h * 128 + n * 16 + lr] = (bf16_t)val;
      }
  }
}

// ---------------- launch ----------------

extern "C" void kernel_launch(void* const* d_in, const int* in_sizes, int n_in, void* d_out,
                              int out_size, void* d_ws, size_t ws_size, hipStream_t stream) {
  const float* hs = (const float*)d_in[0];
  const float* Wqa = (const float*)d_in[1];
  const float* Wqb = (const float*)d_in[2];
  const float* Wkva = (const float*)d_in[3];
  const float* Wkvb = (const float*)d_in[4];
  const float* Wo = (const float*)d_in[5];
  float* out = (float*)d_out;

  char* ws = (char*)d_ws;
  size_t off = 0;
  auto alloc = [&](size_t bytes) {
    void* p = ws + off;
    off += (bytes + 255) & ~(size_t)255;
    return p;
  };
  bf16_t* hsb = (bf16_t*)alloc((size_t)NTOK * 2048 * 2);
  bf16_t* W1t = (bf16_t*)alloc((size_t)2176 * 2048 * 2);
  bf16_t* Wqbt = (bf16_t*)alloc((size_t)2048 * 1536 * 2);
  bf16_t* Wkvbt = (bf16_t*)alloc((size_t)3072 * 512 * 2);
  bf16_t* Wot = (bf16_t*)alloc((size_t)2048 * 2048 * 2);
  bf16_t* lat = (bf16_t*)alloc((size_t)NTOK * 2176 * 2);
  bf16_t* qb = (bf16_t*)alloc((size_t)NTOK * 2048 * 2);
  bf16_t* kvb = (bf16_t*)alloc((size_t)NTOK * 3072 * 2);
  bf16_t* attn = (bf16_t*)alloc((size_t)NTOK * 2048 * 2);
  bf16_t* vT = (bf16_t*)alloc((size_t)32 * 128 * 2048 * 2);
  float* cosT = (float*)alloc((size_t)S_ * 32 * 4);
  float* sinT = (float*)alloc((size_t)S_ * 32 * 4);

  // prep
  cast_bf16_k<<<(NTOK * 2048 / 4 + 255) / 256, 256, 0, stream>>>(hs, hsb, NTOK * 2048);
  transpose_cast_k<<<dim3(1536 / 32, 2048 / 32), 256, 0, stream>>>(Wqa, W1t, 2048, 1536, 1536);
  transpose_cast_k<<<dim3(640 / 32, 2048 / 32), 256, 0, stream>>>(Wkva, W1t + (size_t)1536 * 2048,
                                                                  2048, 576, 640);
  transpose_cast_k<<<dim3(2048 / 32, 1536 / 32), 256, 0, stream>>>(Wqb, Wqbt, 1536, 2048, 2048);
  transpose_cast_k<<<dim3(3072 / 32, 512 / 32), 256, 0, stream>>>(Wkvb, Wkvbt, 512, 3072, 3072);
  transpose_cast_k<<<dim3(2048 / 32, 2048 / 32), 256, 0, stream>>>(Wo, Wot, 2048, 2048, 2048);
  rope_tables_k<<<(S_ * 32 + 255) / 256, 256, 0, stream>>>(cosT, sinT);

  // lat = hsb @ [Wqa | Wkva(pad to 640)]   (4096 x 2176, K=2048)
  gemm_bf16<0><<<dim3(2176 / 128, NTOK / 128), 256, 0, stream>>>(hsb, 2048, W1t, lat, NTOK, 2176,
                                                                 2048, 1.0f);
  // rope k_pe (lat cols 2048..2111)
  rope_apply_k<<<(NTOK * 32 + 255) / 256, 256, 0, stream>>>(lat, cosT, sinT, 2176, 1, 0, 2048);
  // q = q_latent @ Wqb, scaled by 1/sqrt(128)
  const float scale = 0.08838834764831845f;
  gemm_bf16<0><<<dim3(2048 / 128, NTOK / 128), 256, 0, stream>>>(lat, 2176, Wqbt, qb, NTOK, 2048,
                                                                 1536, scale);
  rope_apply_k<<<(NTOK * 16 * 32 + 255) / 256, 256, 0, stream>>>(qb, cosT, sinT, 2048, 16, 128, 64);
  // kv = c_kv @ Wkvb
  gemm_bf16<0><<<dim3(3072 / 128, NTOK / 128), 256, 0, stream>>>(lat + 1536, 2176, Wkvbt, kvb, NTOK,
                                                                 3072, 512, 1.0f);
  // V^T for attention staging
  transpose_v_k<<<dim3(64, 4, 32), 256, 0, stream>>>(kvb, vT);
  // attention (balanced triangle pairing)
  attn_fused<<<dim3(512), 256, 0, stream>>>(qb, kvb, lat, vT, attn);
  // out = attn @ Wo (f32 output)
  gemm_bf16<1><<<dim3(2048 / 128, NTOK / 128), 256, 0, stream>>>(attn, 2048, Wot, out, NTOK, 2048,
                                                                 2048, 1.0f);
}